// Round 14
// baseline (707.118 us; speedup 1.0000x reference)
//
#include <hip/hip_runtime.h>

#define N_NODES  100000
#define N_EDGES  1600000
#define N_GRAPHS 128

// ---- counting-sort CSR build geometry ----
#define BSH      8                       // bucket = dst >> 8  (256 nodes per bucket)
#define BNODES   (1 << BSH)              // 256
#define NBUCK    391                     // ceil(100000/256)
#define NBLK_P1  512                     // edge-pass blocks
#define EPB      (N_EDGES / NBLK_P1)     // 3125 (exact)
#define BKT_SCAN_N   (NBUCK * NBLK_P1)   // 200192
#define SCAN_BLK_BKT 196                 // ceil(200192/1024)
#define SCAN_BLK_NODE 98                 // ceil(100000/1024)

typedef unsigned short u16;
typedef unsigned int   u32;
typedef __attribute__((ext_vector_type(8))) short short8;
typedef __attribute__((ext_vector_type(4))) float f32x4;

__device__ __forceinline__ float bf2f(u16 v) {
  union { u32 i; float f; } u; u.i = ((u32)v) << 16; return u.f;
}
__device__ __forceinline__ u16 f2bf(float f) {
  union { float f; u32 i; } u; u.f = f;
  u32 r = (u.i + 0x7fffu + ((u.i >> 16) & 1u)) >> 16;
  return (u16)r;
}
__device__ __forceinline__ float sigmoid_f(float x) { return 1.f / (1.f + __expf(-x)); }
__device__ __forceinline__ float tanh_f(float x) {
  x = fminf(15.f, fmaxf(-15.f, x));
  float e = __expf(2.f * x);
  return (e - 1.f) / (e + 1.f);
}
__device__ __forceinline__ int geti(const int* __restrict__ p, int i, int is64) {
  return p[is64 ? (2 * i) : i];
}

// Detect whether edge_index / batch are int64 (all sampled odd words == 0) or int32.
__global__ void detect_i64_kernel(const int* __restrict__ ei, const int* __restrict__ batch,
                                  int* __restrict__ flags) {
  int lane = threadIdx.x;  // 64
  {
    long long q = (long long)lane * (3200000 / 2 - 1) / 63;
    int pos = (int)(2 * q + 1);
    unsigned long long m = __ballot(ei[pos] != 0);
    if (lane == 0) flags[0] = (m == 0ull) ? 1 : 0;
  }
  {
    long long q = (long long)lane * (100000 / 2 - 1) / 63;
    int pos = (int)(2 * q + 1);
    unsigned long long m = __ballot(batch[pos] != 0);
    if (lane == 0) flags[1] = (m == 0ull) ? 1 : 0;
  }
}

// ---------------- CSR build: two-level counting sort, zero global atomics ----------------

// P1: per-block LDS bucket histogram -> bcounts[bucket][block] (coalesced store).
__global__ __launch_bounds__(256)
void bucket_hist(const int* __restrict__ ei, const int* __restrict__ flags,
                 int* __restrict__ bcounts) {
  __shared__ int h[NBUCK];
  const int f = flags[0];
  for (int b = threadIdx.x; b < NBUCK; b += 256) h[b] = 0;
  __syncthreads();
  const int e0 = blockIdx.x * EPB;
  for (int i = threadIdx.x; i < EPB; i += 256) {
    int d = geti(ei, N_EDGES + e0 + i, f);
    atomicAdd(&h[d >> BSH], 1);
  }
  __syncthreads();
  for (int b = threadIdx.x; b < NBUCK; b += 256)
    bcounts[b * NBLK_P1 + blockIdx.x] = h[b];
}

// P2: deterministic bucket scatter. LDS cursors seeded from the scanned count matrix.
// Pack: bits [16:0] = src (<2^17), bits [24:17] = dst & 255.
__global__ __launch_bounds__(256)
void bucket_scatter(const int* __restrict__ ei, const int* __restrict__ flags,
                    const int* __restrict__ bbases, u32* __restrict__ bedges) {
  __shared__ int cur[NBUCK];
  const int f = flags[0];
  for (int b = threadIdx.x; b < NBUCK; b += 256)
    cur[b] = bbases[b * NBLK_P1 + blockIdx.x];
  __syncthreads();
  const int e0 = blockIdx.x * EPB;
  for (int i = threadIdx.x; i < EPB; i += 256) {
    int e = e0 + i;
    int d = geti(ei, N_EDGES + e, f);
    int s = geti(ei, e, f);
    int pos = atomicAdd(&cur[d >> BSH], 1);
    bedges[pos] = ((u32)(d & (BNODES - 1)) << 17) | (u32)s;
  }
}

// P3a: per-bucket LDS node histogram -> coalesced counts store.
__global__ __launch_bounds__(256)
void node_count(const u32* __restrict__ bedges, const int* __restrict__ bbases,
                int* __restrict__ counts) {
  __shared__ int h[BNODES];
  const int b = blockIdx.x;
  for (int i = threadIdx.x; i < BNODES; i += 256) h[i] = 0;
  __syncthreads();
  const int beg = bbases[b * NBLK_P1];
  const int end = (b + 1 < NBUCK) ? bbases[(b + 1) * NBLK_P1] : N_EDGES;
  for (int e = beg + threadIdx.x; e < end; e += 256)
    atomicAdd(&h[bedges[e] >> 17], 1);
  __syncthreads();
  const int node0 = b << BSH;
  for (int i = threadIdx.x; i < BNODES; i += 256)
    if (node0 + i < N_NODES) counts[node0 + i] = h[i];
}

// P3b: final CSR scatter into the bucket's contiguous CSR window (L2-resident).
__global__ __launch_bounds__(256)
void final_scatter(const u32* __restrict__ bedges, const int* __restrict__ bbases,
                   const int* __restrict__ offs, int* __restrict__ ssrc) {
  __shared__ int cur[BNODES];
  const int b = blockIdx.x;
  const int node0 = b << BSH;
  for (int i = threadIdx.x; i < BNODES; i += 256)
    cur[i] = (node0 + i < N_NODES) ? offs[node0 + i] : 0;
  __syncthreads();
  const int beg = bbases[b * NBLK_P1];
  const int end = (b + 1 < NBUCK) ? bbases[(b + 1) * NBLK_P1] : N_EDGES;
  for (int e = beg + threadIdx.x; e < end; e += 256) {
    u32 v = bedges[e];
    int pos = atomicAdd(&cur[v >> 17], 1);
    ssrc[pos] = (int)(v & 0x1FFFFu);
  }
}

// ---------------- parameterized exclusive scan ----------------
__global__ __launch_bounds__(1024)
void scanA_kernel(const int* __restrict__ counts, int n, int* __restrict__ blocksums) {
  __shared__ int red[16];
  int i = blockIdx.x * 1024 + threadIdx.x;
  int v = (i < n) ? counts[i] : 0;
  for (int o = 32; o > 0; o >>= 1) v += __shfl_down(v, o, 64);
  int wv = threadIdx.x >> 6, lane = threadIdx.x & 63;
  if (lane == 0) red[wv] = v;
  __syncthreads();
  if (threadIdx.x < 16) {
    int s = red[threadIdx.x];
    for (int o = 8; o > 0; o >>= 1) s += __shfl_down(s, o, 64);
    if (threadIdx.x == 0) blocksums[blockIdx.x] = s;
  }
}

__global__ void scanB_kernel(const int* __restrict__ blocksums, int nblocks,
                             int* __restrict__ blockbase, int* __restrict__ total_out) {
  if (threadIdx.x == 0) {
    int run = 0;
    for (int b = 0; b < nblocks; ++b) { blockbase[b] = run; run += blocksums[b]; }
    if (total_out) *total_out = run;
  }
}

__global__ __launch_bounds__(1024)
void scanC_kernel(const int* __restrict__ counts, int n, const int* __restrict__ blockbase,
                  int* __restrict__ offsets) {
  __shared__ int buf[1024];
  int t = threadIdx.x;
  int i = blockIdx.x * 1024 + t;
  int v = (i < n) ? counts[i] : 0;
  buf[t] = v;
  __syncthreads();
  for (int o = 1; o < 1024; o <<= 1) {
    int add = (t >= o) ? buf[t - o] : 0;
    __syncthreads();
    buf[t] += add;
    __syncthreads();
  }
  if (i < n) offsets[i] = buf[t] - v + blockbase[blockIdx.x];
}

// ---------------- weight prep ----------------
__global__ void transpose_kernel(const float* __restrict__ in, u16* __restrict__ out, int K, int N) {
  int i = blockIdx.x * 256 + threadIdx.x;
  if (i < K * N) {
    int k = i / N, n = i % N;
    out[n * K + k] = f2bf(in[i]);
  }
}

// W'_l[k][c] = sum_j ggnn_w[l][k][j] * w_ih[j][c]   (f32, [3][128][384])
__global__ void wprime_kernel(const float* __restrict__ ggnn_w, const float* __restrict__ w_ih,
                              float* __restrict__ wp) {
  int i = blockIdx.x * 256 + threadIdx.x;
  if (i >= 3 * 128 * 384) return;
  int l = i / (128 * 384), r = i % (128 * 384), k = r / 384, c = r % 384;
  const float* W = ggnn_w + l * 128 * 128;
  float s = 0.f;
  for (int j = 0; j < 128; ++j) s += W[k * 128 + j] * w_ih[j * 384 + c];
  wp[i] = s;
}

// Packed GRU weight: b2q[ci=8][gate=3][quad=4][col=128][e=8] u16 (98304/layer).
// u16 strides: ci=12288, gate=4096, quad=1024, col=8, e=1.
// k = ci*32 + quad*8 + e; column = gate*128 + col. ci<4 <=> k<128 <=> agg path (wp).
__global__ void build_b2q_kernel(const float* __restrict__ wp, const float* __restrict__ w_hh,
                                 u16* __restrict__ b2q) {
  int g = blockIdx.x * 256 + threadIdx.x;
  if (g >= 98304) return;
  int r = g;
  int e    = r & 7;   r >>= 3;
  int col  = r & 127; r >>= 7;
  int quad = r & 3;   r >>= 2;
  int gate = r % 3;   r /= 3;
  int ci   = r;       // 0..7
  int k = ci * 32 + quad * 8 + e;
  int n_lin = gate * 128 + col;
  float v = (k < 128) ? wp[k * 384 + n_lin] : w_hh[(k - 128) * 384 + n_lin];
  b2q[g] = f2bf(v);
}

// ---------------- node projection GEMM (f32 A -> bf16 frags) ----------------
__global__ __launch_bounds__(256)
void nodeproj_gemm(const float* __restrict__ A, const u16* __restrict__ BT,
                   const float* __restrict__ bias, u16* __restrict__ out, int M)
{
  constexpr int K_DIM = 64, N_DIM = 128, NT = 8, NCHUNK = 2;
  __shared__ u16 B_lds[N_DIM * 40];
  const int tid = threadIdx.x, lane = tid & 63, w = tid >> 6;
  const int strip = blockIdx.x * 64;
  const int ksub = (lane >> 4) * 8;
  union Frag { uint4 u; short8 s; };
  Frag af[NCHUNK];
  const int m_node = strip + w * 16 + (lane & 15);
  const bool avalid = (m_node < M);
#pragma unroll
  for (int ci = 0; ci < NCHUNK; ++ci) {
    int k0 = ci * 32 + ksub;
    short8 sv = {0,0,0,0,0,0,0,0};
    if (avalid) {
      const float* p = A + (size_t)m_node * K_DIM + k0;
      float4 f0 = *(const float4*)p;
      float4 f1 = *(const float4*)(p + 4);
      sv[0]=(short)f2bf(f0.x); sv[1]=(short)f2bf(f0.y); sv[2]=(short)f2bf(f0.z); sv[3]=(short)f2bf(f0.w);
      sv[4]=(short)f2bf(f1.x); sv[5]=(short)f2bf(f1.y); sv[6]=(short)f2bf(f1.z); sv[7]=(short)f2bf(f1.w);
    }
    af[ci].s = sv;
  }
  f32x4 acc[NT];
#pragma unroll
  for (int t = 0; t < NT; ++t) acc[t] = {0.f, 0.f, 0.f, 0.f};
  const int boff = (lane & 15) * 40 + ksub;
#pragma unroll
  for (int ci = 0; ci < NCHUNK; ++ci) {
    if (ci) __syncthreads();
    for (int g = tid; g < N_DIM * 4; g += 256) {
      int n = g >> 2, ko = g & 3;
      uint4 bv = *(const uint4*)(BT + (size_t)n * K_DIM + ci * 32 + ko * 8);
      *(uint4*)(&B_lds[n * 40 + ko * 8]) = bv;
    }
    __syncthreads();
    short8 a = af[ci].s;
#pragma unroll
    for (int t = 0; t < NT; ++t) {
      const short8 b = *(const short8*)(&B_lds[t * 16 * 40 + boff]);
      acc[t] = __builtin_amdgcn_mfma_f32_16x16x32_bf16(a, b, acc[t], 0, 0, 0);
    }
  }
  const int mrow = (lane >> 4) * 4;
#pragma unroll
  for (int t = 0; t < NT; ++t) {
    int col = t * 16 + (lane & 15);
    float bv = bias[col];
#pragma unroll
    for (int r = 0; r < 4; ++r) {
      int node = strip + w * 16 + mrow + r;
      if (node < M) out[(size_t)node * N_DIM + col] = f2bf(fmaxf(acc[t][r] + bv, 0.f));
    }
  }
}

// ---------------- GRU GEMM: full-row blocks (64 x 128), clean 256B writebacks ----------------
// Round 14: the "write granularity" theory failed twice — WRITE stayed ~2x with
// both 64B (r10) and 128B (r13) aligned chunks. The invariant across all rounds:
// WRITE is clean (25MB, r2/r4) ONLY when one block produces the full 256B output
// row; split-row blocks' dirty half-lines evict separately (blocks run ~us apart)
// and each line writes twice. Fix structurally: block = 64 rows x ALL 128 cols
// (grid 1563), 8 waves of 16 rows x 64 cols (the GEMM geometry that ran inside
// round-12's fused kernel). B staged per-ci double-buffered (2x24KB, 8 barriers);
// epilogue stages the 64x128 tile in the retired B buffer -> full 256B-row writes.
// LDS 48KB -> 3 blocks/CU. Decisive check: WRITE_SIZE 49.8 -> ~25.6MB.
__global__ __launch_bounds__(512, 6)
void gru_gemm(const u16* __restrict__ agg, const u16* __restrict__ h,
              const u16* __restrict__ b2q, const float* __restrict__ b_ih,
              const float* __restrict__ b_hh, u16* __restrict__ hout, int M)
{
  __shared__ u16 Bbuf[2][12288];  // 2 x 24KB: per-ci [gate=3][quad=4][col=128][e=8]
  const int tid  = threadIdx.x;
  const int lane = tid & 63;
  const int w    = tid >> 6;        // 0..7
  const int bid  = blockIdx.x;
  // bijective XCD-chunked remap: nwg = 1563 = 8*195 + 3 (m204 formula)
  const int xcd = bid & 7, idx = bid >> 3;
  const int linear = ((xcd < 3) ? xcd * 196 : 3 * 196 + (xcd - 3) * 195) + idx;
  const int strip = linear * 64;
  const int rw   = (w & 3) * 16;    // row group
  const int ch   = (w >> 2) * 64;   // col half base
  const int lrow = lane & 15;
  const int quad = lane >> 4;

  const int node = strip + rw + lrow;
  const bool nv = (node < M);

  union Frag { uint4 u; short8 s8; };
  Frag a[2];
  const uint4 zz = {0u, 0u, 0u, 0u};
  auto lda = [&](int ci, int p) {
    const u16* ap = (ci < 4) ? (agg + ci * 32 + quad * 8) : (h + (ci - 4) * 32 + quad * 8);
    a[p].u = nv ? *(const uint4*)(ap + (size_t)node * 128) : zz;
  };

  // stage one ci slice (24KB): pure linear copy, 1536 uint4, 3/thread.
  auto stageB = [&](int ci, int buf) {
    const u16* src = b2q + (size_t)ci * 12288;
#pragma unroll
    for (int k = 0; k < 3; ++k) {
      int i4 = tid + k * 512;
      *(uint4*)(&Bbuf[buf][i4 * 8]) = *(const uint4*)(src + i4 * 8);
    }
  };

  lda(0, 0);
  lda(1, 1);
  stageB(0, 0);

  f32x4 ar[4], az[4], ain[4], ahn[4];
#pragma unroll
  for (int t = 0; t < 4; ++t) {
    ar[t] = {0.f,0.f,0.f,0.f}; az[t] = {0.f,0.f,0.f,0.f};
    ain[t] = {0.f,0.f,0.f,0.f}; ahn[t] = {0.f,0.f,0.f,0.f};
  }

  __syncthreads();   // B(0) staged

#pragma unroll
  for (int ci = 0; ci < 8; ++ci) {
    const int p = ci & 1;
    if (ci < 7) stageB(ci + 1, p ^ 1);   // fill other buffer while computing
    short8 A = a[p].s8;
    if (ci < 6) lda(ci + 2, p);          // 2-deep A prefetch
#pragma unroll
    for (int t = 0; t < 4; ++t) {
      const u16* lb = &Bbuf[p][quad * 1024 + (ch + t * 16 + lrow) * 8];
      short8 br = *(const short8*)(lb);
      short8 bz = *(const short8*)(lb + 4096);
      short8 bg = *(const short8*)(lb + 8192);
      ar[t] = __builtin_amdgcn_mfma_f32_16x16x32_bf16(A, br, ar[t], 0, 0, 0);
      az[t] = __builtin_amdgcn_mfma_f32_16x16x32_bf16(A, bz, az[t], 0, 0, 0);
      if (ci < 4) ain[t] = __builtin_amdgcn_mfma_f32_16x16x32_bf16(A, bg, ain[t], 0, 0, 0);
      else        ahn[t] = __builtin_amdgcn_mfma_f32_16x16x32_bf16(A, bg, ahn[t], 0, 0, 0);
    }
    __syncthreads();
  }

  // Epilogue: GRU nonlinearity -> stage 64x128 tile in retired Bbuf -> full-row writes.
  u16* Olds = (u16*)Bbuf;          // 16KB needed, 48KB available
#pragma unroll
  for (int t = 0; t < 4; ++t) {
    const int c = ch + t * 16 + lrow;           // global column
    const float brr = b_ih[c] + b_hh[c];
    const float bzz = b_ih[128 + c] + b_hh[128 + c];
    const float bin = b_ih[256 + c];
    const float bhn = b_hh[256 + c];
#pragma unroll
    for (int r = 0; r < 4; ++r) {
      const int lr   = rw + quad * 4 + r;       // row within block (0..63)
      const int nrow = strip + lr;
      u16 val = 0;
      if (nrow < M) {
        float rg = sigmoid_f(ar[t][r] + brr);
        float zg = sigmoid_f(az[t][r] + bzz);
        float hv = ahn[t][r] + bhn;
        float ng = tanh_f(ain[t][r] + bin + rg * hv);
        float hp = bf2f(h[(size_t)nrow * 128 + c]);
        val = f2bf((1.f - zg) * ng + zg * hp);
      }
      Olds[lr * 128 + c] = val;
    }
  }
  __syncthreads();
  // Full-row writeback: 64 rows x 16 uint4 = 1024 stores, 2 per thread.
#pragma unroll
  for (int rr = 0; rr < 2; ++rr) {
    const int row = (tid >> 4) + rr * 32;
    const int c16 = tid & 15;
    const int nrow = strip + row;
    if (nrow < M)
      *(uint4*)(&hout[(size_t)nrow * 128 + c16 * 8]) = *(const uint4*)(&Olds[row * 128 + c16 * 8]);
  }
}

// ---------------- CSR aggregation, 16 edges in flight ----------------
__global__ __launch_bounds__(256)
void agg_kernel(const u16* __restrict__ m, const int* __restrict__ ssrc,
                const int* __restrict__ offsets, u16* __restrict__ agg)
{
  int node = blockIdx.x * 4 + (threadIdx.x >> 6);
  int lane = threadIdx.x & 63;
  if (node >= N_NODES) return;
  const int g = lane >> 4, l = lane & 15;
  int beg = offsets[node], end = offsets[node + 1];
  float s[8] = {0.f,0.f,0.f,0.f,0.f,0.f,0.f,0.f};
  for (int e = beg; e < end; e += 16) {   // 4 groups of 4 edges in flight
    uint4 v0 = {0u,0u,0u,0u}, v1 = {0u,0u,0u,0u};
    uint4 v2 = {0u,0u,0u,0u}, v3 = {0u,0u,0u,0u};
    int e0 = e + g, e1 = e + 4 + g, e2 = e + 8 + g, e3 = e + 12 + g;
    if (e0 < end) { int src = ssrc[e0]; v0 = *(const uint4*)(m + (size_t)src * 128 + l * 8); }
    if (e1 < end) { int src = ssrc[e1]; v1 = *(const uint4*)(m + (size_t)src * 128 + l * 8); }
    if (e2 < end) { int src = ssrc[e2]; v2 = *(const uint4*)(m + (size_t)src * 128 + l * 8); }
    if (e3 < end) { int src = ssrc[e3]; v3 = *(const uint4*)(m + (size_t)src * 128 + l * 8); }
    u32 w0[4] = {v0.x, v0.y, v0.z, v0.w};
    u32 w1[4] = {v1.x, v1.y, v1.z, v1.w};
    u32 w2[4] = {v2.x, v2.y, v2.z, v2.w};
    u32 w3[4] = {v3.x, v3.y, v3.z, v3.w};
#pragma unroll
    for (int i = 0; i < 4; ++i) {
      s[2*i]   += (bf2f((u16)(w0[i] & 0xffffu)) + bf2f((u16)(w1[i] & 0xffffu)))
                + (bf2f((u16)(w2[i] & 0xffffu)) + bf2f((u16)(w3[i] & 0xffffu)));
      s[2*i+1] += (bf2f((u16)(w0[i] >> 16))     + bf2f((u16)(w1[i] >> 16)))
                + (bf2f((u16)(w2[i] >> 16))     + bf2f((u16)(w3[i] >> 16)));
    }
  }
#pragma unroll
  for (int i = 0; i < 8; ++i) {
    s[i] += __shfl_xor(s[i], 16, 64);
    s[i] += __shfl_xor(s[i], 32, 64);
  }
  if (g == 0) {
    uint4 o;
    o.x = (u32)f2bf(s[0]) | ((u32)f2bf(s[1]) << 16);
    o.y = (u32)f2bf(s[2]) | ((u32)f2bf(s[3]) << 16);
    o.z = (u32)f2bf(s[4]) | ((u32)f2bf(s[5]) << 16);
    o.w = (u32)f2bf(s[6]) | ((u32)f2bf(s[7]) << 16);
    *(uint4*)(agg + (size_t)node * 128 + l * 8) = o;
  }
}

// ---------------- parallel segmented mean-pool (batch is sorted) ----------------
__global__ __launch_bounds__(256)
void pool_kernel(const u16* __restrict__ h, const int* __restrict__ batch,
                 const int* __restrict__ flags, float* __restrict__ sums)
{
  const int c = threadIdx.x & 127;
  const int half = threadIdx.x >> 7;
  const int base = blockIdx.x * 128;
  const int f = flags[1];
  int gcur = -1; float s = 0.f;
  for (int i = half; i < 128; i += 2) {
    int n = base + i;
    if (n >= N_NODES) break;
    int g = geti(batch, n, f);
    if (g != gcur) {
      if (gcur >= 0) atomicAdd(&sums[gcur * 128 + c], s);
      s = 0.f; gcur = g;
    }
    s += bf2f(h[(size_t)n * 128 + c]);
  }
  if (gcur >= 0) atomicAdd(&sums[gcur * 128 + c], s);
}

// ---------------- doc proj + LN + fusion + heads, f32 (one block per graph) ----------------
__global__ __launch_bounds__(256)
void head2_kernel(const float* __restrict__ sums, const int* __restrict__ batch,
                  const int* __restrict__ flags,
                  const float* __restrict__ doc, const float* __restrict__ doc_w, const float* __restrict__ doc_b,
                  const float* __restrict__ ln_g, const float* __restrict__ ln_b,
                  const float* __restrict__ fus_w, const float* __restrict__ fus_b,
                  const float* __restrict__ task_w, const float* __restrict__ task_b,
                  const float* __restrict__ time_w, const float* __restrict__ time_b,
                  float* __restrict__ out_task, float* __restrict__ out_time)
{
  const int g = blockIdx.x;
  const int t = threadIdx.x;
  __shared__ float fusion[256];
  __shared__ float fh[128];
  __shared__ float dpart[256];
  __shared__ int seg[2];

  if (t < 2) {
    int f = flags[1];
    int target = g + t, lo = 0, hi = N_NODES;
    while (lo < hi) { int mid = (lo + hi) >> 1; if (geti(batch, mid, f) < target) lo = mid + 1; else hi = mid; }
    seg[t] = lo;
  }
  {
    int c = t & 127, kh = t >> 7;
    float s = 0.f;
    for (int k = kh * 384; k < kh * 384 + 384; ++k) s += doc[g * 768 + k] * doc_w[k * 128 + c];
    dpart[t] = s;
  }
  __syncthreads();

  if (t < 128) {
    float cnt = (float)(seg[1] - seg[0]);
    fusion[t] = sums[g * 128 + t] / fmaxf(cnt, 1.f);
  } else {
    int c = t - 128;
    fusion[t] = fmaxf(dpart[c] + dpart[c + 128] + doc_b[c], 0.f);
  }
  __syncthreads();

  float mu = 0.f;
  for (int i = 0; i < 256; ++i) mu += fusion[i];
  mu *= (1.f / 256.f);
  float var = 0.f;
  for (int i = 0; i < 256; ++i) { float d = fusion[i] - mu; var += d * d; }
  var *= (1.f / 256.f);
  float inv = rsqrtf(var + 1e-5f);
  float norm = (fusion[t] - mu) * inv * ln_g[t] + ln_b[t];
  __syncthreads();
  fusion[t] = norm;
  __syncthreads();

  if (t < 128) {
    float s = 0.f;
    for (int k = 0; k < 256; ++k) s += fusion[k] * fus_w[k * 128 + t];
    s += fus_b[t];
    fh[t] = fmaxf(s, 0.f);
  }
  __syncthreads();

  if (t < 32) {
    float s = 0.f;
    for (int k = 0; k < 128; ++k) s += fh[k] * task_w[k * 32 + t];
    s += task_b[t];
    out_task[g * 32 + t] = s;
  }
  if (t == 32) {
    float s = 0.f;
    for (int k = 0; k < 128; ++k) s += fh[k] * time_w[k];
    s += time_b[0];
    out_time[g] = s;
  }
}

// ---------------- launch ----------------
extern "C" void kernel_launch(void* const* d_in, const int* in_sizes, int n_in,
                              void* d_out, int out_size, void* d_ws, size_t ws_size,
                              hipStream_t stream)
{
  const float* x        = (const float*)d_in[0];
  const float* doc      = (const float*)d_in[1];
  const int*   ei       = (const int*)d_in[2];
  const int*   batch    = (const int*)d_in[3];
  const float* node_w   = (const float*)d_in[4];
  const float* node_b   = (const float*)d_in[5];
  const float* ggnn_w   = (const float*)d_in[6];
  const float* gru_w_ih = (const float*)d_in[7];
  const float* gru_b_ih = (const float*)d_in[8];
  const float* gru_w_hh = (const float*)d_in[9];
  const float* gru_b_hh = (const float*)d_in[10];
  const float* doc_w    = (const float*)d_in[11];
  const float* doc_b    = (const float*)d_in[12];
  const float* ln_g     = (const float*)d_in[13];
  const float* ln_b     = (const float*)d_in[14];
  const float* fus_w    = (const float*)d_in[15];
  const float* fus_b    = (const float*)d_in[16];
  const float* task_w   = (const float*)d_in[17];
  const float* task_b   = (const float*)d_in[18];
  const float* time_w   = (const float*)d_in[19];
  const float* time_b   = (const float*)d_in[20];

  char* ws = (char*)d_ws;
  size_t off = 0;
  auto alloc = [&](size_t bytes) -> void* {
    void* p = ws + off;
    off = (off + bytes + 255) & ~(size_t)255;
    return p;
  };
  u16* aggb    = (u16*)alloc((size_t)N_NODES * 128 * 2);   // 25.6 MB
  u16* hA      = (u16*)alloc((size_t)N_NODES * 128 * 2);
  u16* hB      = (u16*)alloc((size_t)N_NODES * 128 * 2);
  u16* nwT     = (u16*)alloc(64 * 128 * 2);
  u16* b2q     = (u16*)alloc(3 * 98304 * 2);
  float* wp    = (float*)alloc(3 * 128 * 384 * 4);
  float* sums  = (float*)alloc(N_GRAPHS * 128 * 4);
  int* counts  = (int*)alloc((size_t)N_NODES * 4);
  int* offs    = (int*)alloc((size_t)(N_NODES + 1) * 4);
  int* ssrc    = (int*)alloc((size_t)N_EDGES * 4);
  int* bsum    = (int*)alloc(SCAN_BLK_BKT * 4);
  int* bbase   = (int*)alloc(SCAN_BLK_BKT * 4);
  int* flags   = (int*)alloc(2 * 4);

  // CSR-build scratch ALIASED into aggb (dead before agg_kernel writes aggb).
  u32* bedges  = (u32*)aggb;                                        // 6,400,000 B
  int* bcounts = (int*)((char*)aggb + 6400000);                     // 800,768 B (256-aligned)
  int* bbases  = (int*)((char*)aggb + 7200768);                     // 800,772 B (256-aligned)

  hipMemsetAsync(sums, 0, (size_t)N_GRAPHS * 128 * 4, stream);

  detect_i64_kernel<<<1, 64, 0, stream>>>(ei, batch, flags);

  // CSR build: counting sort, zero global atomics.
  bucket_hist<<<NBLK_P1, 256, 0, stream>>>(ei, flags, bcounts);
  scanA_kernel<<<SCAN_BLK_BKT, 1024, 0, stream>>>(bcounts, BKT_SCAN_N, bsum);
  scanB_kernel<<<1, 64, 0, stream>>>(bsum, SCAN_BLK_BKT, bbase, (int*)nullptr);
  scanC_kernel<<<SCAN_BLK_BKT, 1024, 0, stream>>>(bcounts, BKT_SCAN_N, bbase, bbases);
  bucket_scatter<<<NBLK_P1, 256, 0, stream>>>(ei, flags, bbases, bedges);
  node_count<<<NBUCK, 256, 0, stream>>>(bedges, bbases, counts);
  scanA_kernel<<<SCAN_BLK_NODE, 1024, 0, stream>>>(counts, N_NODES, bsum);
  scanB_kernel<<<1, 64, 0, stream>>>(bsum, SCAN_BLK_NODE, bbase, offs + N_NODES);
  scanC_kernel<<<SCAN_BLK_NODE, 1024, 0, stream>>>(counts, N_NODES, bbase, offs);
  final_scatter<<<NBUCK, 256, 0, stream>>>(bedges, bbases, offs, ssrc);

  transpose_kernel<<<(64 * 128 + 255) / 256, 256, 0, stream>>>(node_w, nwT, 64, 128);
  wprime_kernel<<<(3 * 128 * 384 + 255) / 256, 256, 0, stream>>>(ggnn_w, gru_w_ih, wp);
  for (int l = 0; l < 3; ++l)
    build_b2q_kernel<<<(98304 + 255) / 256, 256, 0, stream>>>(
        wp + l * 128 * 384, gru_w_hh, b2q + (size_t)l * 98304);

  const int GB = (N_NODES + 63) / 64;    // 1563; gru uses one block per 64-row strip
  nodeproj_gemm<<<GB, 256, 0, stream>>>(x, nwT, node_b, hA, N_NODES);

  u16* hcur = hA;
  u16* hnext = hB;
  for (int l = 0; l < 3; ++l) {
    agg_kernel<<<(N_NODES + 3) / 4, 256, 0, stream>>>(hcur, ssrc, offs, aggb);
    gru_gemm<<<GB, 512, 0, stream>>>(aggb, hcur, b2q + (size_t)l * 98304,
                                     gru_b_ih, gru_b_hh, hnext, N_NODES);
    u16* tmp = hcur; hcur = hnext; hnext = tmp;
  }

  pool_kernel<<<(N_NODES + 127) / 128, 256, 0, stream>>>(hcur, batch, flags, sums);

  float* out_task = (float*)d_out;
  float* out_time = out_task + N_GRAPHS * 32;
  head2_kernel<<<N_GRAPHS, 256, 0, stream>>>(sums, batch, flags, doc, doc_w, doc_b, ln_g, ln_b,
                                             fus_w, fus_b, task_w, task_b, time_w, time_b,
                                             out_task, out_time);
}

// Round 15
// 627.962 us; speedup vs baseline: 1.1261x; 1.1261x over previous
//
#include <hip/hip_runtime.h>

#define N_NODES  100000
#define N_EDGES  1600000
#define N_GRAPHS 128

// ---- counting-sort CSR build geometry ----
#define BSH      8                       // bucket = dst >> 8  (256 nodes per bucket)
#define BNODES   (1 << BSH)              // 256
#define NBUCK    391                     // ceil(100000/256)
#define NBLK_P1  512                     // edge-pass blocks
#define EPB      (N_EDGES / NBLK_P1)     // 3125 (exact)
#define BKT_SCAN_N   (NBUCK * NBLK_P1)   // 200192
#define SCAN_BLK_BKT 196                 // ceil(200192/1024)
#define SCAN_BLK_NODE 98                 // ceil(100000/1024)

typedef unsigned short u16;
typedef unsigned int   u32;
typedef __attribute__((ext_vector_type(8))) short short8;
typedef __attribute__((ext_vector_type(4))) float f32x4;

__device__ __forceinline__ float bf2f(u16 v) {
  union { u32 i; float f; } u; u.i = ((u32)v) << 16; return u.f;
}
__device__ __forceinline__ u16 f2bf(float f) {
  union { float f; u32 i; } u; u.f = f;
  u32 r = (u.i + 0x7fffu + ((u.i >> 16) & 1u)) >> 16;
  return (u16)r;
}
__device__ __forceinline__ float sigmoid_f(float x) { return 1.f / (1.f + __expf(-x)); }
__device__ __forceinline__ float tanh_f(float x) {
  x = fminf(15.f, fmaxf(-15.f, x));
  float e = __expf(2.f * x);
  return (e - 1.f) / (e + 1.f);
}
__device__ __forceinline__ int geti(const int* __restrict__ p, int i, int is64) {
  return p[is64 ? (2 * i) : i];
}

// Detect whether edge_index / batch are int64 (all sampled odd words == 0) or int32.
__global__ void detect_i64_kernel(const int* __restrict__ ei, const int* __restrict__ batch,
                                  int* __restrict__ flags) {
  int lane = threadIdx.x;  // 64
  {
    long long q = (long long)lane * (3200000 / 2 - 1) / 63;
    int pos = (int)(2 * q + 1);
    unsigned long long m = __ballot(ei[pos] != 0);
    if (lane == 0) flags[0] = (m == 0ull) ? 1 : 0;
  }
  {
    long long q = (long long)lane * (100000 / 2 - 1) / 63;
    int pos = (int)(2 * q + 1);
    unsigned long long m = __ballot(batch[pos] != 0);
    if (lane == 0) flags[1] = (m == 0ull) ? 1 : 0;
  }
}

// ---------------- CSR build: two-level counting sort, zero global atomics ----------------

// P1: per-block LDS bucket histogram -> bcounts[bucket][block] (coalesced store).
__global__ __launch_bounds__(256)
void bucket_hist(const int* __restrict__ ei, const int* __restrict__ flags,
                 int* __restrict__ bcounts) {
  __shared__ int h[NBUCK];
  const int f = flags[0];
  for (int b = threadIdx.x; b < NBUCK; b += 256) h[b] = 0;
  __syncthreads();
  const int e0 = blockIdx.x * EPB;
  for (int i = threadIdx.x; i < EPB; i += 256) {
    int d = geti(ei, N_EDGES + e0 + i, f);
    atomicAdd(&h[d >> BSH], 1);
  }
  __syncthreads();
  for (int b = threadIdx.x; b < NBUCK; b += 256)
    bcounts[b * NBLK_P1 + blockIdx.x] = h[b];
}

// P2: deterministic bucket scatter. LDS cursors seeded from the scanned count matrix.
// Pack: bits [16:0] = src (<2^17), bits [24:17] = dst & 255.
__global__ __launch_bounds__(256)
void bucket_scatter(const int* __restrict__ ei, const int* __restrict__ flags,
                    const int* __restrict__ bbases, u32* __restrict__ bedges) {
  __shared__ int cur[NBUCK];
  const int f = flags[0];
  for (int b = threadIdx.x; b < NBUCK; b += 256)
    cur[b] = bbases[b * NBLK_P1 + blockIdx.x];
  __syncthreads();
  const int e0 = blockIdx.x * EPB;
  for (int i = threadIdx.x; i < EPB; i += 256) {
    int e = e0 + i;
    int d = geti(ei, N_EDGES + e, f);
    int s = geti(ei, e, f);
    int pos = atomicAdd(&cur[d >> BSH], 1);
    bedges[pos] = ((u32)(d & (BNODES - 1)) << 17) | (u32)s;
  }
}

// P3a: per-bucket LDS node histogram -> coalesced counts store.
__global__ __launch_bounds__(256)
void node_count(const u32* __restrict__ bedges, const int* __restrict__ bbases,
                int* __restrict__ counts) {
  __shared__ int h[BNODES];
  const int b = blockIdx.x;
  for (int i = threadIdx.x; i < BNODES; i += 256) h[i] = 0;
  __syncthreads();
  const int beg = bbases[b * NBLK_P1];
  const int end = (b + 1 < NBUCK) ? bbases[(b + 1) * NBLK_P1] : N_EDGES;
  for (int e = beg + threadIdx.x; e < end; e += 256)
    atomicAdd(&h[bedges[e] >> 17], 1);
  __syncthreads();
  const int node0 = b << BSH;
  for (int i = threadIdx.x; i < BNODES; i += 256)
    if (node0 + i < N_NODES) counts[node0 + i] = h[i];
}

// P3b: final CSR scatter into the bucket's contiguous CSR window (L2-resident).
__global__ __launch_bounds__(256)
void final_scatter(const u32* __restrict__ bedges, const int* __restrict__ bbases,
                   const int* __restrict__ offs, int* __restrict__ ssrc) {
  __shared__ int cur[BNODES];
  const int b = blockIdx.x;
  const int node0 = b << BSH;
  for (int i = threadIdx.x; i < BNODES; i += 256)
    cur[i] = (node0 + i < N_NODES) ? offs[node0 + i] : 0;
  __syncthreads();
  const int beg = bbases[b * NBLK_P1];
  const int end = (b + 1 < NBUCK) ? bbases[(b + 1) * NBLK_P1] : N_EDGES;
  for (int e = beg + threadIdx.x; e < end; e += 256) {
    u32 v = bedges[e];
    int pos = atomicAdd(&cur[v >> 17], 1);
    ssrc[pos] = (int)(v & 0x1FFFFu);
  }
}

// ---------------- parameterized exclusive scan ----------------
__global__ __launch_bounds__(1024)
void scanA_kernel(const int* __restrict__ counts, int n, int* __restrict__ blocksums) {
  __shared__ int red[16];
  int i = blockIdx.x * 1024 + threadIdx.x;
  int v = (i < n) ? counts[i] : 0;
  for (int o = 32; o > 0; o >>= 1) v += __shfl_down(v, o, 64);
  int wv = threadIdx.x >> 6, lane = threadIdx.x & 63;
  if (lane == 0) red[wv] = v;
  __syncthreads();
  if (threadIdx.x < 16) {
    int s = red[threadIdx.x];
    for (int o = 8; o > 0; o >>= 1) s += __shfl_down(s, o, 64);
    if (threadIdx.x == 0) blocksums[blockIdx.x] = s;
  }
}

__global__ void scanB_kernel(const int* __restrict__ blocksums, int nblocks,
                             int* __restrict__ blockbase, int* __restrict__ total_out) {
  if (threadIdx.x == 0) {
    int run = 0;
    for (int b = 0; b < nblocks; ++b) { blockbase[b] = run; run += blocksums[b]; }
    if (total_out) *total_out = run;
  }
}

__global__ __launch_bounds__(1024)
void scanC_kernel(const int* __restrict__ counts, int n, const int* __restrict__ blockbase,
                  int* __restrict__ offsets) {
  __shared__ int buf[1024];
  int t = threadIdx.x;
  int i = blockIdx.x * 1024 + t;
  int v = (i < n) ? counts[i] : 0;
  buf[t] = v;
  __syncthreads();
  for (int o = 1; o < 1024; o <<= 1) {
    int add = (t >= o) ? buf[t - o] : 0;
    __syncthreads();
    buf[t] += add;
    __syncthreads();
  }
  if (i < n) offsets[i] = buf[t] - v + blockbase[blockIdx.x];
}

// ---------------- weight prep ----------------
__global__ void transpose_kernel(const float* __restrict__ in, u16* __restrict__ out, int K, int N) {
  int i = blockIdx.x * 256 + threadIdx.x;
  if (i < K * N) {
    int k = i / N, n = i % N;
    out[n * K + k] = f2bf(in[i]);
  }
}

// W'_l[k][c] = sum_j ggnn_w[l][k][j] * w_ih[j][c]   (f32, [3][128][384])
__global__ void wprime_kernel(const float* __restrict__ ggnn_w, const float* __restrict__ w_ih,
                              float* __restrict__ wp) {
  int i = blockIdx.x * 256 + threadIdx.x;
  if (i >= 3 * 128 * 384) return;
  int l = i / (128 * 384), r = i % (128 * 384), k = r / 384, c = r % 384;
  const float* W = ggnn_w + l * 128 * 128;
  float s = 0.f;
  for (int j = 0; j < 128; ++j) s += W[k * 128 + j] * w_ih[j * 384 + c];
  wp[i] = s;
}

// Packed GRU weight: b2q[ci=8][gate=3][quad=4][col=128][e=8] u16 (98304/layer).
// u16 strides: ci=12288, gate=4096, quad=1024, col=8, e=1.
// k = ci*32 + quad*8 + e; column = gate*128 + col. ci<4 <=> k<128 <=> agg path (wp).
__global__ void build_b2q_kernel(const float* __restrict__ wp, const float* __restrict__ w_hh,
                                 u16* __restrict__ b2q) {
  int g = blockIdx.x * 256 + threadIdx.x;
  if (g >= 98304) return;
  int r = g;
  int e    = r & 7;   r >>= 3;
  int col  = r & 127; r >>= 7;
  int quad = r & 3;   r >>= 2;
  int gate = r % 3;   r /= 3;
  int ci   = r;       // 0..7
  int k = ci * 32 + quad * 8 + e;
  int n_lin = gate * 128 + col;
  float v = (k < 128) ? wp[k * 384 + n_lin] : w_hh[(k - 128) * 384 + n_lin];
  b2q[g] = f2bf(v);
}

// ---------------- node projection GEMM (f32 A -> bf16 frags) ----------------
__global__ __launch_bounds__(256)
void nodeproj_gemm(const float* __restrict__ A, const u16* __restrict__ BT,
                   const float* __restrict__ bias, u16* __restrict__ out, int M)
{
  constexpr int K_DIM = 64, N_DIM = 128, NT = 8, NCHUNK = 2;
  __shared__ u16 B_lds[N_DIM * 40];
  const int tid = threadIdx.x, lane = tid & 63, w = tid >> 6;
  const int strip = blockIdx.x * 64;
  const int ksub = (lane >> 4) * 8;
  union Frag { uint4 u; short8 s; };
  Frag af[NCHUNK];
  const int m_node = strip + w * 16 + (lane & 15);
  const bool avalid = (m_node < M);
#pragma unroll
  for (int ci = 0; ci < NCHUNK; ++ci) {
    int k0 = ci * 32 + ksub;
    short8 sv = {0,0,0,0,0,0,0,0};
    if (avalid) {
      const float* p = A + (size_t)m_node * K_DIM + k0;
      float4 f0 = *(const float4*)p;
      float4 f1 = *(const float4*)(p + 4);
      sv[0]=(short)f2bf(f0.x); sv[1]=(short)f2bf(f0.y); sv[2]=(short)f2bf(f0.z); sv[3]=(short)f2bf(f0.w);
      sv[4]=(short)f2bf(f1.x); sv[5]=(short)f2bf(f1.y); sv[6]=(short)f2bf(f1.z); sv[7]=(short)f2bf(f1.w);
    }
    af[ci].s = sv;
  }
  f32x4 acc[NT];
#pragma unroll
  for (int t = 0; t < NT; ++t) acc[t] = {0.f, 0.f, 0.f, 0.f};
  const int boff = (lane & 15) * 40 + ksub;
#pragma unroll
  for (int ci = 0; ci < NCHUNK; ++ci) {
    if (ci) __syncthreads();
    for (int g = tid; g < N_DIM * 4; g += 256) {
      int n = g >> 2, ko = g & 3;
      uint4 bv = *(const uint4*)(BT + (size_t)n * K_DIM + ci * 32 + ko * 8);
      *(uint4*)(&B_lds[n * 40 + ko * 8]) = bv;
    }
    __syncthreads();
    short8 a = af[ci].s;
#pragma unroll
    for (int t = 0; t < NT; ++t) {
      const short8 b = *(const short8*)(&B_lds[t * 16 * 40 + boff]);
      acc[t] = __builtin_amdgcn_mfma_f32_16x16x32_bf16(a, b, acc[t], 0, 0, 0);
    }
  }
  const int mrow = (lane >> 4) * 4;
#pragma unroll
  for (int t = 0; t < NT; ++t) {
    int col = t * 16 + (lane & 15);
    float bv = bias[col];
#pragma unroll
    for (int r = 0; r < 4; ++r) {
      int node = strip + w * 16 + mrow + r;
      if (node < M) out[(size_t)node * N_DIM + col] = f2bf(fmaxf(acc[t][r] + bv, 0.f));
    }
  }
}

// ---------------- GRU GEMM: 32-row full-width blocks, no spill ----------------
// Round 15: round-14's 64x128 blocks spilled — 64 acc + ~40 arch = 104 regs >
// the 85-reg cap from launch_bounds(512,6) on the unified VGPR/AGPR file ->
// WRITE 125MB / FETCH 84.6MB scratch signature. Keep the full-row invariant
// (only full-256B-row blocks write cleanly: r2/r4 = 25MB; all split-row
// variants 2x) but shrink to 32 rows x 128 cols (grid 3125 = N/32 exactly).
// 8 waves: row-half (w&1)*16, col-quarter (w>>1)*32 -> 2 col-tiles/wave =
// 32 acc regs (r13's measured shape: VGPR=40, no spill). B per-ci
// double-buffered (2x24KB linear copy); epilogue stages 32x128 tile in
// retired Bbuf -> full-row writes. LDS 48KB -> 3 blocks/CU (75% occ).
__global__ __launch_bounds__(512, 6)
void gru_gemm(const u16* __restrict__ agg, const u16* __restrict__ h,
              const u16* __restrict__ b2q, const float* __restrict__ b_ih,
              const float* __restrict__ b_hh, u16* __restrict__ hout, int M)
{
  __shared__ u16 Bbuf[2][12288];  // 2 x 24KB: per-ci [gate=3][quad=4][col=128][e=8]
  const int tid  = threadIdx.x;
  const int lane = tid & 63;
  const int w    = tid >> 6;        // 0..7
  const int bid  = blockIdx.x;
  // bijective XCD-chunked remap: nwg = 3125 = 8*390 + 5 (m204 formula)
  const int xcd = bid & 7, idx = bid >> 3;
  const int linear = ((xcd < 5) ? xcd * 391 : 5 * 391 + (xcd - 5) * 390) + idx;
  const int strip = linear * 32;
  const int rw   = (w & 1) * 16;    // row half
  const int cq   = (w >> 1) * 32;   // col quarter base
  const int lrow = lane & 15;
  const int quad = lane >> 4;

  const int node = strip + rw + lrow;
  const bool nv = (node < M);

  union Frag { uint4 u; short8 s8; };
  Frag a[2];
  const uint4 zz = {0u, 0u, 0u, 0u};
  auto lda = [&](int ci, int p) {
    const u16* ap = (ci < 4) ? (agg + ci * 32 + quad * 8) : (h + (ci - 4) * 32 + quad * 8);
    a[p].u = nv ? *(const uint4*)(ap + (size_t)node * 128) : zz;
  };

  // stage one ci slice (24KB): pure linear copy, 1536 uint4, 3/thread.
  auto stageB = [&](int ci, int buf) {
    const u16* src = b2q + (size_t)ci * 12288;
#pragma unroll
    for (int k = 0; k < 3; ++k) {
      int i4 = tid + k * 512;
      *(uint4*)(&Bbuf[buf][i4 * 8]) = *(const uint4*)(src + i4 * 8);
    }
  };

  lda(0, 0);
  lda(1, 1);
  stageB(0, 0);

  f32x4 ar[2], az[2], ain[2], ahn[2];
#pragma unroll
  for (int t = 0; t < 2; ++t) {
    ar[t] = {0.f,0.f,0.f,0.f}; az[t] = {0.f,0.f,0.f,0.f};
    ain[t] = {0.f,0.f,0.f,0.f}; ahn[t] = {0.f,0.f,0.f,0.f};
  }

  __syncthreads();   // B(0) staged

#pragma unroll
  for (int ci = 0; ci < 8; ++ci) {
    const int p = ci & 1;
    if (ci < 7) stageB(ci + 1, p ^ 1);   // fill other buffer while computing
    short8 A = a[p].s8;
    if (ci < 6) lda(ci + 2, p);          // 2-deep A prefetch
#pragma unroll
    for (int t = 0; t < 2; ++t) {
      const u16* lb = &Bbuf[p][quad * 1024 + (cq + t * 16 + lrow) * 8];
      short8 br = *(const short8*)(lb);
      short8 bz = *(const short8*)(lb + 4096);
      short8 bg = *(const short8*)(lb + 8192);
      ar[t] = __builtin_amdgcn_mfma_f32_16x16x32_bf16(A, br, ar[t], 0, 0, 0);
      az[t] = __builtin_amdgcn_mfma_f32_16x16x32_bf16(A, bz, az[t], 0, 0, 0);
      if (ci < 4) ain[t] = __builtin_amdgcn_mfma_f32_16x16x32_bf16(A, bg, ain[t], 0, 0, 0);
      else        ahn[t] = __builtin_amdgcn_mfma_f32_16x16x32_bf16(A, bg, ahn[t], 0, 0, 0);
    }
    __syncthreads();
  }

  // Epilogue: GRU nonlinearity -> stage 32x128 tile (8KB) in retired Bbuf ->
  // full 256B-row writes (one block owns the whole row).
  u16* Olds = (u16*)Bbuf;
#pragma unroll
  for (int t = 0; t < 2; ++t) {
    const int c = cq + t * 16 + lrow;           // global column
    const float brr = b_ih[c] + b_hh[c];
    const float bzz = b_ih[128 + c] + b_hh[128 + c];
    const float bin = b_ih[256 + c];
    const float bhn = b_hh[256 + c];
#pragma unroll
    for (int r = 0; r < 4; ++r) {
      const int lr   = rw + quad * 4 + r;       // row within block (0..31)
      const int nrow = strip + lr;
      u16 val = 0;
      if (nrow < M) {
        float rg = sigmoid_f(ar[t][r] + brr);
        float zg = sigmoid_f(az[t][r] + bzz);
        float hv = ahn[t][r] + bhn;
        float ng = tanh_f(ain[t][r] + bin + rg * hv);
        float hp = bf2f(h[(size_t)nrow * 128 + c]);
        val = f2bf((1.f - zg) * ng + zg * hp);
      }
      Olds[lr * 128 + c] = val;
    }
  }
  __syncthreads();
  // Full-row writeback: 32 rows x 16 uint4 = 512 stores, 1 per thread.
  {
    const int row = tid >> 4, c16 = tid & 15;
    const int nrow = strip + row;
    if (nrow < M)
      *(uint4*)(&hout[(size_t)nrow * 128 + c16 * 8]) = *(const uint4*)(&Olds[row * 128 + c16 * 8]);
  }
}

// ---------------- CSR aggregation, 16 edges in flight ----------------
__global__ __launch_bounds__(256)
void agg_kernel(const u16* __restrict__ m, const int* __restrict__ ssrc,
                const int* __restrict__ offsets, u16* __restrict__ agg)
{
  int node = blockIdx.x * 4 + (threadIdx.x >> 6);
  int lane = threadIdx.x & 63;
  if (node >= N_NODES) return;
  const int g = lane >> 4, l = lane & 15;
  int beg = offsets[node], end = offsets[node + 1];
  float s[8] = {0.f,0.f,0.f,0.f,0.f,0.f,0.f,0.f};
  for (int e = beg; e < end; e += 16) {   // 4 groups of 4 edges in flight
    uint4 v0 = {0u,0u,0u,0u}, v1 = {0u,0u,0u,0u};
    uint4 v2 = {0u,0u,0u,0u}, v3 = {0u,0u,0u,0u};
    int e0 = e + g, e1 = e + 4 + g, e2 = e + 8 + g, e3 = e + 12 + g;
    if (e0 < end) { int src = ssrc[e0]; v0 = *(const uint4*)(m + (size_t)src * 128 + l * 8); }
    if (e1 < end) { int src = ssrc[e1]; v1 = *(const uint4*)(m + (size_t)src * 128 + l * 8); }
    if (e2 < end) { int src = ssrc[e2]; v2 = *(const uint4*)(m + (size_t)src * 128 + l * 8); }
    if (e3 < end) { int src = ssrc[e3]; v3 = *(const uint4*)(m + (size_t)src * 128 + l * 8); }
    u32 w0[4] = {v0.x, v0.y, v0.z, v0.w};
    u32 w1[4] = {v1.x, v1.y, v1.z, v1.w};
    u32 w2[4] = {v2.x, v2.y, v2.z, v2.w};
    u32 w3[4] = {v3.x, v3.y, v3.z, v3.w};
#pragma unroll
    for (int i = 0; i < 4; ++i) {
      s[2*i]   += (bf2f((u16)(w0[i] & 0xffffu)) + bf2f((u16)(w1[i] & 0xffffu)))
                + (bf2f((u16)(w2[i] & 0xffffu)) + bf2f((u16)(w3[i] & 0xffffu)));
      s[2*i+1] += (bf2f((u16)(w0[i] >> 16))     + bf2f((u16)(w1[i] >> 16)))
                + (bf2f((u16)(w2[i] >> 16))     + bf2f((u16)(w3[i] >> 16)));
    }
  }
#pragma unroll
  for (int i = 0; i < 8; ++i) {
    s[i] += __shfl_xor(s[i], 16, 64);
    s[i] += __shfl_xor(s[i], 32, 64);
  }
  if (g == 0) {
    uint4 o;
    o.x = (u32)f2bf(s[0]) | ((u32)f2bf(s[1]) << 16);
    o.y = (u32)f2bf(s[2]) | ((u32)f2bf(s[3]) << 16);
    o.z = (u32)f2bf(s[4]) | ((u32)f2bf(s[5]) << 16);
    o.w = (u32)f2bf(s[6]) | ((u32)f2bf(s[7]) << 16);
    *(uint4*)(agg + (size_t)node * 128 + l * 8) = o;
  }
}

// ---------------- parallel segmented mean-pool (batch is sorted) ----------------
__global__ __launch_bounds__(256)
void pool_kernel(const u16* __restrict__ h, const int* __restrict__ batch,
                 const int* __restrict__ flags, float* __restrict__ sums)
{
  const int c = threadIdx.x & 127;
  const int half = threadIdx.x >> 7;
  const int base = blockIdx.x * 128;
  const int f = flags[1];
  int gcur = -1; float s = 0.f;
  for (int i = half; i < 128; i += 2) {
    int n = base + i;
    if (n >= N_NODES) break;
    int g = geti(batch, n, f);
    if (g != gcur) {
      if (gcur >= 0) atomicAdd(&sums[gcur * 128 + c], s);
      s = 0.f; gcur = g;
    }
    s += bf2f(h[(size_t)n * 128 + c]);
  }
  if (gcur >= 0) atomicAdd(&sums[gcur * 128 + c], s);
}

// ---------------- doc proj + LN + fusion + heads, f32 (one block per graph) ----------------
__global__ __launch_bounds__(256)
void head2_kernel(const float* __restrict__ sums, const int* __restrict__ batch,
                  const int* __restrict__ flags,
                  const float* __restrict__ doc, const float* __restrict__ doc_w, const float* __restrict__ doc_b,
                  const float* __restrict__ ln_g, const float* __restrict__ ln_b,
                  const float* __restrict__ fus_w, const float* __restrict__ fus_b,
                  const float* __restrict__ task_w, const float* __restrict__ task_b,
                  const float* __restrict__ time_w, const float* __restrict__ time_b,
                  float* __restrict__ out_task, float* __restrict__ out_time)
{
  const int g = blockIdx.x;
  const int t = threadIdx.x;
  __shared__ float fusion[256];
  __shared__ float fh[128];
  __shared__ float dpart[256];
  __shared__ int seg[2];

  if (t < 2) {
    int f = flags[1];
    int target = g + t, lo = 0, hi = N_NODES;
    while (lo < hi) { int mid = (lo + hi) >> 1; if (geti(batch, mid, f) < target) lo = mid + 1; else hi = mid; }
    seg[t] = lo;
  }
  {
    int c = t & 127, kh = t >> 7;
    float s = 0.f;
    for (int k = kh * 384; k < kh * 384 + 384; ++k) s += doc[g * 768 + k] * doc_w[k * 128 + c];
    dpart[t] = s;
  }
  __syncthreads();

  if (t < 128) {
    float cnt = (float)(seg[1] - seg[0]);
    fusion[t] = sums[g * 128 + t] / fmaxf(cnt, 1.f);
  } else {
    int c = t - 128;
    fusion[t] = fmaxf(dpart[c] + dpart[c + 128] + doc_b[c], 0.f);
  }
  __syncthreads();

  float mu = 0.f;
  for (int i = 0; i < 256; ++i) mu += fusion[i];
  mu *= (1.f / 256.f);
  float var = 0.f;
  for (int i = 0; i < 256; ++i) { float d = fusion[i] - mu; var += d * d; }
  var *= (1.f / 256.f);
  float inv = rsqrtf(var + 1e-5f);
  float norm = (fusion[t] - mu) * inv * ln_g[t] + ln_b[t];
  __syncthreads();
  fusion[t] = norm;
  __syncthreads();

  if (t < 128) {
    float s = 0.f;
    for (int k = 0; k < 256; ++k) s += fusion[k] * fus_w[k * 128 + t];
    s += fus_b[t];
    fh[t] = fmaxf(s, 0.f);
  }
  __syncthreads();

  if (t < 32) {
    float s = 0.f;
    for (int k = 0; k < 128; ++k) s += fh[k] * task_w[k * 32 + t];
    s += task_b[t];
    out_task[g * 32 + t] = s;
  }
  if (t == 32) {
    float s = 0.f;
    for (int k = 0; k < 128; ++k) s += fh[k] * time_w[k];
    s += time_b[0];
    out_time[g] = s;
  }
}

// ---------------- launch ----------------
extern "C" void kernel_launch(void* const* d_in, const int* in_sizes, int n_in,
                              void* d_out, int out_size, void* d_ws, size_t ws_size,
                              hipStream_t stream)
{
  const float* x        = (const float*)d_in[0];
  const float* doc      = (const float*)d_in[1];
  const int*   ei       = (const int*)d_in[2];
  const int*   batch    = (const int*)d_in[3];
  const float* node_w   = (const float*)d_in[4];
  const float* node_b   = (const float*)d_in[5];
  const float* ggnn_w   = (const float*)d_in[6];
  const float* gru_w_ih = (const float*)d_in[7];
  const float* gru_b_ih = (const float*)d_in[8];
  const float* gru_w_hh = (const float*)d_in[9];
  const float* gru_b_hh = (const float*)d_in[10];
  const float* doc_w    = (const float*)d_in[11];
  const float* doc_b    = (const float*)d_in[12];
  const float* ln_g     = (const float*)d_in[13];
  const float* ln_b     = (const float*)d_in[14];
  const float* fus_w    = (const float*)d_in[15];
  const float* fus_b    = (const float*)d_in[16];
  const float* task_w   = (const float*)d_in[17];
  const float* task_b   = (const float*)d_in[18];
  const float* time_w   = (const float*)d_in[19];
  const float* time_b   = (const float*)d_in[20];

  char* ws = (char*)d_ws;
  size_t off = 0;
  auto alloc = [&](size_t bytes) -> void* {
    void* p = ws + off;
    off = (off + bytes + 255) & ~(size_t)255;
    return p;
  };
  u16* aggb    = (u16*)alloc((size_t)N_NODES * 128 * 2);   // 25.6 MB
  u16* hA      = (u16*)alloc((size_t)N_NODES * 128 * 2);
  u16* hB      = (u16*)alloc((size_t)N_NODES * 128 * 2);
  u16* nwT     = (u16*)alloc(64 * 128 * 2);
  u16* b2q     = (u16*)alloc(3 * 98304 * 2);
  float* wp    = (float*)alloc(3 * 128 * 384 * 4);
  float* sums  = (float*)alloc(N_GRAPHS * 128 * 4);
  int* counts  = (int*)alloc((size_t)N_NODES * 4);
  int* offs    = (int*)alloc((size_t)(N_NODES + 1) * 4);
  int* ssrc    = (int*)alloc((size_t)N_EDGES * 4);
  int* bsum    = (int*)alloc(SCAN_BLK_BKT * 4);
  int* bbase   = (int*)alloc(SCAN_BLK_BKT * 4);
  int* flags   = (int*)alloc(2 * 4);

  // CSR-build scratch ALIASED into aggb (dead before agg_kernel writes aggb).
  u32* bedges  = (u32*)aggb;                                        // 6,400,000 B
  int* bcounts = (int*)((char*)aggb + 6400000);                     // 800,768 B (256-aligned)
  int* bbases  = (int*)((char*)aggb + 7200768);                     // 800,772 B (256-aligned)

  hipMemsetAsync(sums, 0, (size_t)N_GRAPHS * 128 * 4, stream);

  detect_i64_kernel<<<1, 64, 0, stream>>>(ei, batch, flags);

  // CSR build: counting sort, zero global atomics.
  bucket_hist<<<NBLK_P1, 256, 0, stream>>>(ei, flags, bcounts);
  scanA_kernel<<<SCAN_BLK_BKT, 1024, 0, stream>>>(bcounts, BKT_SCAN_N, bsum);
  scanB_kernel<<<1, 64, 0, stream>>>(bsum, SCAN_BLK_BKT, bbase, (int*)nullptr);
  scanC_kernel<<<SCAN_BLK_BKT, 1024, 0, stream>>>(bcounts, BKT_SCAN_N, bbase, bbases);
  bucket_scatter<<<NBLK_P1, 256, 0, stream>>>(ei, flags, bbases, bedges);
  node_count<<<NBUCK, 256, 0, stream>>>(bedges, bbases, counts);
  scanA_kernel<<<SCAN_BLK_NODE, 1024, 0, stream>>>(counts, N_NODES, bsum);
  scanB_kernel<<<1, 64, 0, stream>>>(bsum, SCAN_BLK_NODE, bbase, offs + N_NODES);
  scanC_kernel<<<SCAN_BLK_NODE, 1024, 0, stream>>>(counts, N_NODES, bbase, offs);
  final_scatter<<<NBUCK, 256, 0, stream>>>(bedges, bbases, offs, ssrc);

  transpose_kernel<<<(64 * 128 + 255) / 256, 256, 0, stream>>>(node_w, nwT, 64, 128);
  wprime_kernel<<<(3 * 128 * 384 + 255) / 256, 256, 0, stream>>>(ggnn_w, gru_w_ih, wp);
  for (int l = 0; l < 3; ++l)
    build_b2q_kernel<<<(98304 + 255) / 256, 256, 0, stream>>>(
        wp + l * 128 * 384, gru_w_hh, b2q + (size_t)l * 98304);

  const int GB = (N_NODES + 63) / 64;        // 1563
  const int GBGRU = N_NODES / 32;            // 3125 (exact) — 32-row full-width blocks
  nodeproj_gemm<<<GB, 256, 0, stream>>>(x, nwT, node_b, hA, N_NODES);

  u16* hcur = hA;
  u16* hnext = hB;
  for (int l = 0; l < 3; ++l) {
    agg_kernel<<<(N_NODES + 3) / 4, 256, 0, stream>>>(hcur, ssrc, offs, aggb);
    gru_gemm<<<GBGRU, 512, 0, stream>>>(aggb, hcur, b2q + (size_t)l * 98304,
                                        gru_b_ih, gru_b_hh, hnext, N_NODES);
    u16* tmp = hcur; hcur = hnext; hnext = tmp;
  }

  pool_kernel<<<(N_NODES + 127) / 128, 256, 0, stream>>>(hcur, batch, flags, sums);

  float* out_task = (float*)d_out;
  float* out_time = out_task + N_GRAPHS * 32;
  head2_kernel<<<N_GRAPHS, 256, 0, stream>>>(sums, batch, flags, doc, doc_w, doc_b, ln_g, ln_b,
                                             fus_w, fus_b, task_w, task_b, time_w, time_b,
                                             out_task, out_time);
}

// Round 16
// 599.219 us; speedup vs baseline: 1.1801x; 1.0480x over previous
//
#include <hip/hip_runtime.h>

#define N_NODES  100000
#define N_EDGES  1600000
#define N_GRAPHS 128

// ---- counting-sort CSR build geometry ----
#define BSH      8                       // bucket = dst >> 8  (256 nodes per bucket)
#define BNODES   (1 << BSH)              // 256
#define NBUCK    391                     // ceil(100000/256)
#define NBLK_P1  512                     // edge-pass blocks
#define EPB      (N_EDGES / NBLK_P1)     // 3125 (exact)
#define BKT_SCAN_N   (NBUCK * NBLK_P1)   // 200192
#define SCAN_BLK_BKT 196                 // ceil(200192/1024)
#define SCAN_BLK_NODE 98                 // ceil(100000/1024)

typedef unsigned short u16;
typedef unsigned int   u32;
typedef __attribute__((ext_vector_type(8))) short short8;
typedef __attribute__((ext_vector_type(4))) float f32x4;

__device__ __forceinline__ float bf2f(u16 v) {
  union { u32 i; float f; } u; u.i = ((u32)v) << 16; return u.f;
}
__device__ __forceinline__ u16 f2bf(float f) {
  union { float f; u32 i; } u; u.f = f;
  u32 r = (u.i + 0x7fffu + ((u.i >> 16) & 1u)) >> 16;
  return (u16)r;
}
__device__ __forceinline__ float sigmoid_f(float x) { return 1.f / (1.f + __expf(-x)); }
__device__ __forceinline__ float tanh_f(float x) {
  x = fminf(15.f, fmaxf(-15.f, x));
  float e = __expf(2.f * x);
  return (e - 1.f) / (e + 1.f);
}
__device__ __forceinline__ int geti(const int* __restrict__ p, int i, int is64) {
  return p[is64 ? (2 * i) : i];
}

// Detect whether edge_index / batch are int64 (all sampled odd words == 0) or int32.
__global__ void detect_i64_kernel(const int* __restrict__ ei, const int* __restrict__ batch,
                                  int* __restrict__ flags) {
  int lane = threadIdx.x;  // 64
  {
    long long q = (long long)lane * (3200000 / 2 - 1) / 63;
    int pos = (int)(2 * q + 1);
    unsigned long long m = __ballot(ei[pos] != 0);
    if (lane == 0) flags[0] = (m == 0ull) ? 1 : 0;
  }
  {
    long long q = (long long)lane * (100000 / 2 - 1) / 63;
    int pos = (int)(2 * q + 1);
    unsigned long long m = __ballot(batch[pos] != 0);
    if (lane == 0) flags[1] = (m == 0ull) ? 1 : 0;
  }
}

// ---------------- CSR build: two-level counting sort, zero global atomics ----------------

// P1: per-block LDS bucket histogram -> bcounts[bucket][block] (coalesced store).
__global__ __launch_bounds__(256)
void bucket_hist(const int* __restrict__ ei, const int* __restrict__ flags,
                 int* __restrict__ bcounts) {
  __shared__ int h[NBUCK];
  const int f = flags[0];
  for (int b = threadIdx.x; b < NBUCK; b += 256) h[b] = 0;
  __syncthreads();
  const int e0 = blockIdx.x * EPB;
  for (int i = threadIdx.x; i < EPB; i += 256) {
    int d = geti(ei, N_EDGES + e0 + i, f);
    atomicAdd(&h[d >> BSH], 1);
  }
  __syncthreads();
  for (int b = threadIdx.x; b < NBUCK; b += 256)
    bcounts[b * NBLK_P1 + blockIdx.x] = h[b];
}

// P2: deterministic bucket scatter. LDS cursors seeded from the scanned count matrix.
// Pack: bits [16:0] = src (<2^17), bits [24:17] = dst & 255.
__global__ __launch_bounds__(256)
void bucket_scatter(const int* __restrict__ ei, const int* __restrict__ flags,
                    const int* __restrict__ bbases, u32* __restrict__ bedges) {
  __shared__ int cur[NBUCK];
  const int f = flags[0];
  for (int b = threadIdx.x; b < NBUCK; b += 256)
    cur[b] = bbases[b * NBLK_P1 + blockIdx.x];
  __syncthreads();
  const int e0 = blockIdx.x * EPB;
  for (int i = threadIdx.x; i < EPB; i += 256) {
    int e = e0 + i;
    int d = geti(ei, N_EDGES + e, f);
    int s = geti(ei, e, f);
    int pos = atomicAdd(&cur[d >> BSH], 1);
    bedges[pos] = ((u32)(d & (BNODES - 1)) << 17) | (u32)s;
  }
}

// P3a: per-bucket LDS node histogram -> coalesced counts store.
__global__ __launch_bounds__(256)
void node_count(const u32* __restrict__ bedges, const int* __restrict__ bbases,
                int* __restrict__ counts) {
  __shared__ int h[BNODES];
  const int b = blockIdx.x;
  for (int i = threadIdx.x; i < BNODES; i += 256) h[i] = 0;
  __syncthreads();
  const int beg = bbases[b * NBLK_P1];
  const int end = (b + 1 < NBUCK) ? bbases[(b + 1) * NBLK_P1] : N_EDGES;
  for (int e = beg + threadIdx.x; e < end; e += 256)
    atomicAdd(&h[bedges[e] >> 17], 1);
  __syncthreads();
  const int node0 = b << BSH;
  for (int i = threadIdx.x; i < BNODES; i += 256)
    if (node0 + i < N_NODES) counts[node0 + i] = h[i];
}

// P3b: final CSR scatter into the bucket's contiguous CSR window (L2-resident).
__global__ __launch_bounds__(256)
void final_scatter(const u32* __restrict__ bedges, const int* __restrict__ bbases,
                   const int* __restrict__ offs, int* __restrict__ ssrc) {
  __shared__ int cur[BNODES];
  const int b = blockIdx.x;
  const int node0 = b << BSH;
  for (int i = threadIdx.x; i < BNODES; i += 256)
    cur[i] = (node0 + i < N_NODES) ? offs[node0 + i] : 0;
  __syncthreads();
  const int beg = bbases[b * NBLK_P1];
  const int end = (b + 1 < NBUCK) ? bbases[(b + 1) * NBLK_P1] : N_EDGES;
  for (int e = beg + threadIdx.x; e < end; e += 256) {
    u32 v = bedges[e];
    int pos = atomicAdd(&cur[v >> 17], 1);
    ssrc[pos] = (int)(v & 0x1FFFFu);
  }
}

// ---------------- parameterized exclusive scan ----------------
__global__ __launch_bounds__(1024)
void scanA_kernel(const int* __restrict__ counts, int n, int* __restrict__ blocksums) {
  __shared__ int red[16];
  int i = blockIdx.x * 1024 + threadIdx.x;
  int v = (i < n) ? counts[i] : 0;
  for (int o = 32; o > 0; o >>= 1) v += __shfl_down(v, o, 64);
  int wv = threadIdx.x >> 6, lane = threadIdx.x & 63;
  if (lane == 0) red[wv] = v;
  __syncthreads();
  if (threadIdx.x < 16) {
    int s = red[threadIdx.x];
    for (int o = 8; o > 0; o >>= 1) s += __shfl_down(s, o, 64);
    if (threadIdx.x == 0) blocksums[blockIdx.x] = s;
  }
}

__global__ void scanB_kernel(const int* __restrict__ blocksums, int nblocks,
                             int* __restrict__ blockbase, int* __restrict__ total_out) {
  if (threadIdx.x == 0) {
    int run = 0;
    for (int b = 0; b < nblocks; ++b) { blockbase[b] = run; run += blocksums[b]; }
    if (total_out) *total_out = run;
  }
}

__global__ __launch_bounds__(1024)
void scanC_kernel(const int* __restrict__ counts, int n, const int* __restrict__ blockbase,
                  int* __restrict__ offsets) {
  __shared__ int buf[1024];
  int t = threadIdx.x;
  int i = blockIdx.x * 1024 + t;
  int v = (i < n) ? counts[i] : 0;
  buf[t] = v;
  __syncthreads();
  for (int o = 1; o < 1024; o <<= 1) {
    int add = (t >= o) ? buf[t - o] : 0;
    __syncthreads();
    buf[t] += add;
    __syncthreads();
  }
  if (i < n) offsets[i] = buf[t] - v + blockbase[blockIdx.x];
}

// ---------------- weight prep ----------------
__global__ void transpose_kernel(const float* __restrict__ in, u16* __restrict__ out, int K, int N) {
  int i = blockIdx.x * 256 + threadIdx.x;
  if (i < K * N) {
    int k = i / N, n = i % N;
    out[n * K + k] = f2bf(in[i]);
  }
}

// W'_l[k][c] = sum_j ggnn_w[l][k][j] * w_ih[j][c]   (f32, [3][128][384])
__global__ void wprime_kernel(const float* __restrict__ ggnn_w, const float* __restrict__ w_ih,
                              float* __restrict__ wp) {
  int i = blockIdx.x * 256 + threadIdx.x;
  if (i >= 3 * 128 * 384) return;
  int l = i / (128 * 384), r = i % (128 * 384), k = r / 384, c = r % 384;
  const float* W = ggnn_w + l * 128 * 128;
  float s = 0.f;
  for (int j = 0; j < 128; ++j) s += W[k * 128 + j] * w_ih[j * 384 + c];
  wp[i] = s;
}

// Packed GRU weight, LDS-mirror layout (quad-major inner order for
// bank-conflict-free ds_read_b128 — 16-lane phases read 256 contiguous bytes):
// b2q[oc=8][half=2][ci4=4][gate=3][quad=4][col=16][e=8] u16 (98304 per layer).
// u16 strides: oc=12288, half=6144, ci4=1536, gate=512, quad=128, col=8, e=1.
// k = half*128 + ci4*32 + quad*8 + e; column = gate*128 + oc*16 + col.
__global__ void build_b2q_kernel(const float* __restrict__ wp, const float* __restrict__ w_hh,
                                 u16* __restrict__ b2q) {
  int g = blockIdx.x * 256 + threadIdx.x;
  if (g >= 98304) return;
  int r = g;
  int e    = r & 7;  r >>= 3;
  int col  = r & 15; r >>= 4;
  int quad = r & 3;  r >>= 2;
  int gate = r % 3;  r /= 3;
  int ci4  = r & 3;  r >>= 2;
  int half = r & 1;  r >>= 1;
  int oc   = r;      // 0..7
  int k = half * 128 + ci4 * 32 + quad * 8 + e;
  int n_lin = gate * 128 + oc * 16 + col;
  float v = (k < 128) ? wp[k * 384 + n_lin] : w_hh[(k - 128) * 384 + n_lin];
  b2q[g] = f2bf(v);
}

// ---------------- node projection GEMM (f32 A -> bf16 frags) ----------------
__global__ __launch_bounds__(256)
void nodeproj_gemm(const float* __restrict__ A, const u16* __restrict__ BT,
                   const float* __restrict__ bias, u16* __restrict__ out, int M)
{
  constexpr int K_DIM = 64, N_DIM = 128, NT = 8, NCHUNK = 2;
  __shared__ u16 B_lds[N_DIM * 40];
  const int tid = threadIdx.x, lane = tid & 63, w = tid >> 6;
  const int strip = blockIdx.x * 64;
  const int ksub = (lane >> 4) * 8;
  union Frag { uint4 u; short8 s; };
  Frag af[NCHUNK];
  const int m_node = strip + w * 16 + (lane & 15);
  const bool avalid = (m_node < M);
#pragma unroll
  for (int ci = 0; ci < NCHUNK; ++ci) {
    int k0 = ci * 32 + ksub;
    short8 sv = {0,0,0,0,0,0,0,0};
    if (avalid) {
      const float* p = A + (size_t)m_node * K_DIM + k0;
      float4 f0 = *(const float4*)p;
      float4 f1 = *(const float4*)(p + 4);
      sv[0]=(short)f2bf(f0.x); sv[1]=(short)f2bf(f0.y); sv[2]=(short)f2bf(f0.z); sv[3]=(short)f2bf(f0.w);
      sv[4]=(short)f2bf(f1.x); sv[5]=(short)f2bf(f1.y); sv[6]=(short)f2bf(f1.z); sv[7]=(short)f2bf(f1.w);
    }
    af[ci].s = sv;
  }
  f32x4 acc[NT];
#pragma unroll
  for (int t = 0; t < NT; ++t) acc[t] = {0.f, 0.f, 0.f, 0.f};
  const int boff = (lane & 15) * 40 + ksub;
#pragma unroll
  for (int ci = 0; ci < NCHUNK; ++ci) {
    if (ci) __syncthreads();
    for (int g = tid; g < N_DIM * 4; g += 256) {
      int n = g >> 2, ko = g & 3;
      uint4 bv = *(const uint4*)(BT + (size_t)n * K_DIM + ci * 32 + ko * 8);
      *(uint4*)(&B_lds[n * 40 + ko * 8]) = bv;
    }
    __syncthreads();
    short8 a = af[ci].s;
#pragma unroll
    for (int t = 0; t < NT; ++t) {
      const short8 b = *(const short8*)(&B_lds[t * 16 * 40 + boff]);
      acc[t] = __builtin_amdgcn_mfma_f32_16x16x32_bf16(a, b, acc[t], 0, 0, 0);
    }
  }
  const int mrow = (lane >> 4) * 4;
#pragma unroll
  for (int t = 0; t < NT; ++t) {
    int col = t * 16 + (lane & 15);
    float bv = bias[col];
#pragma unroll
    for (int r = 0; r < 4; ++r) {
      int node = strip + w * 16 + mrow + r;
      if (node < M) out[(size_t)node * N_DIM + col] = f2bf(fmaxf(acc[t][r] + bv, 0.f));
    }
  }
}

// ---------------- GRU GEMM: octant-pair blocks, sector-aligned writes ----------------
// Measured-best gru variant (round 9 config, 62.6us): block = 64 rows x 32 cols
// (octant pair; each wave computes two 16x16 tiles sharing one A), B staged
// half-K in 24KB LDS (quad-major, conflict-free), epilogue stages the 64x32
// tile in LDS and writes aligned 64B sectors. launch_bounds(256,6).
__global__ __launch_bounds__(256, 6)
void gru_gemm(const u16* __restrict__ agg, const u16* __restrict__ h,
              const u16* __restrict__ b2q, const float* __restrict__ b_ih,
              const float* __restrict__ b_hh, u16* __restrict__ hout, int M)
{
  __shared__ u16 Blds[12288];  // 24KB: [t=2][ci4=4][gate=3][quad=4][col=16][e=8]
  const int tid  = threadIdx.x;
  const int lane = tid & 63;
  const int w    = tid >> 6;                       // wave -> 16-row substrip
  const int bid  = blockIdx.x;
  // bijective XCD-chunked remap for nwg = 6252 = 8*781 + 4 (m204 formula)
  const int xcd = bid & 7, idx = bid >> 3;
  const int linear = ((xcd < 4) ? xcd * 782 : 4 * 782 + (xcd - 4) * 781) + idx;
  const int op    = linear & 3;                    // octant pair -> cols [op*32, op*32+32)
  const int strip = (linear >> 2) * 64;
  const int lrow = lane & 15;
  const int quad = lane >> 4;

  const int node = strip + w * 16 + lrow;
  const bool nv = (node < M);
  const u16* qsrc0 = b2q + (size_t)(op * 2)     * 12288;  // octant oc0
  const u16* qsrc1 = b2q + (size_t)(op * 2 + 1) * 12288;  // octant oc1

  union Frag { uint4 u; short8 s8; };
  Frag a[2];
  const uint4 zz = {0u, 0u, 0u, 0u};
  auto lda = [&](int ci, int p) {
    const u16* ap = (ci < 4) ? (agg + ci * 32 + quad * 8) : (h + (ci - 4) * 32 + quad * 8);
    a[p].u = nv ? *(const uint4*)(ap + (size_t)node * 128) : zz;
  };

  lda(0, 0);
  lda(1, 1);
  // stage half 0 (ci 0..3) for both octants: linear uint4 copies (768 each)
  for (int i2 = tid; i2 < 768; i2 += 256) {
    *(uint4*)(&Blds[i2 * 8])        = *(const uint4*)(qsrc0 + i2 * 8);
    *(uint4*)(&Blds[6144 + i2 * 8]) = *(const uint4*)(qsrc1 + i2 * 8);
  }

  f32x4 ar[2], az[2], ain[2], ahn[2];
#pragma unroll
  for (int t = 0; t < 2; ++t) {
    ar[t] = {0.f,0.f,0.f,0.f}; az[t] = {0.f,0.f,0.f,0.f};
    ain[t] = {0.f,0.f,0.f,0.f}; ahn[t] = {0.f,0.f,0.f,0.f};
  }

  __syncthreads();   // half-0 staged

#pragma unroll
  for (int ci = 0; ci < 8; ++ci) {
    if (ci == 4) {
      __syncthreads();   // everyone done reading half 0
      for (int i2 = tid; i2 < 768; i2 += 256) {
        *(uint4*)(&Blds[i2 * 8])        = *(const uint4*)(qsrc0 + 6144 + i2 * 8);
        *(uint4*)(&Blds[6144 + i2 * 8]) = *(const uint4*)(qsrc1 + 6144 + i2 * 8);
      }
      __syncthreads();   // half-1 staged
    }
    const int p = ci & 1;
    short8 A = a[p].s8;
    if (ci < 6) lda(ci + 2, p);   // 2-deep A prefetch
#pragma unroll
    for (int t = 0; t < 2; ++t) {
      const u16* lb = &Blds[t * 6144 + (ci & 3) * 1536 + quad * 128 + lrow * 8];
      short8 br = *(const short8*)(lb);
      short8 bz = *(const short8*)(lb + 512);
      short8 bg = *(const short8*)(lb + 1024);
      ar[t] = __builtin_amdgcn_mfma_f32_16x16x32_bf16(A, br, ar[t], 0, 0, 0);
      az[t] = __builtin_amdgcn_mfma_f32_16x16x32_bf16(A, bz, az[t], 0, 0, 0);
      if (ci < 4) ain[t] = __builtin_amdgcn_mfma_f32_16x16x32_bf16(A, bg, ain[t], 0, 0, 0);
      else        ahn[t] = __builtin_amdgcn_mfma_f32_16x16x32_bf16(A, bg, ahn[t], 0, 0, 0);
    }
  }

  // Epilogue: compute into LDS stage (reuse Blds), then sector-aligned writeback.
  __syncthreads();                 // all ds_reads of B done -> safe to overwrite
  u16* Olds = (u16*)Blds;          // [row=64][col=32]
#pragma unroll
  for (int t = 0; t < 2; ++t) {
    const int c = op * 32 + t * 16 + lrow;      // global column
    const float brr = b_ih[c] + b_hh[c];
    const float bzz = b_ih[128 + c] + b_hh[128 + c];
    const float bin = b_ih[256 + c];
    const float bhn = b_hh[256 + c];
#pragma unroll
    for (int r = 0; r < 4; ++r) {
      const int lr   = w * 16 + quad * 4 + r;   // row within block (0..63)
      const int nrow = strip + lr;
      u16 val = 0;
      if (nrow < M) {
        float rg = sigmoid_f(ar[t][r] + brr);
        float zg = sigmoid_f(az[t][r] + bzz);
        float hv = ahn[t][r] + bhn;
        float ng = tanh_f(ain[t][r] + bin + rg * hv);
        float hp = bf2f(h[(size_t)nrow * 128 + c]);
        val = f2bf((1.f - zg) * ng + zg * hp);
      }
      Olds[lr * 32 + t * 16 + lrow] = val;
    }
  }
  __syncthreads();
  {
    const int row = tid >> 2, c4 = tid & 3;     // 64 rows x 4 uint4 (64B/row)
    const int nrow = strip + row;
    if (nrow < M)
      *(uint4*)(&hout[(size_t)nrow * 128 + op * 32 + c4 * 8]) =
          *(const uint4*)(&Olds[row * 32 + c4 * 8]);
  }
}

// ---------------- CSR aggregation, row-vectorized ----------------
__global__ __launch_bounds__(256)
void agg_kernel(const u16* __restrict__ m, const int* __restrict__ ssrc,
                const int* __restrict__ offsets, u16* __restrict__ agg)
{
  int node = blockIdx.x * 4 + (threadIdx.x >> 6);
  int lane = threadIdx.x & 63;
  if (node >= N_NODES) return;
  const int g = lane >> 4, l = lane & 15;
  int beg = offsets[node], end = offsets[node + 1];
  float s[8] = {0.f,0.f,0.f,0.f,0.f,0.f,0.f,0.f};
  for (int e = beg; e < end; e += 8) {   // 2 groups of 4 edges in flight
    uint4 v0 = {0u,0u,0u,0u}, v1 = {0u,0u,0u,0u};
    int e0 = e + g, e1 = e + 4 + g;
    if (e0 < end) { int src = ssrc[e0]; v0 = *(const uint4*)(m + (size_t)src * 128 + l * 8); }
    if (e1 < end) { int src = ssrc[e1]; v1 = *(const uint4*)(m + (size_t)src * 128 + l * 8); }
    u32 w0[4] = {v0.x, v0.y, v0.z, v0.w};
    u32 w1[4] = {v1.x, v1.y, v1.z, v1.w};
#pragma unroll
    for (int i = 0; i < 4; ++i) {
      s[2*i]   += bf2f((u16)(w0[i] & 0xffffu)) + bf2f((u16)(w1[i] & 0xffffu));
      s[2*i+1] += bf2f((u16)(w0[i] >> 16))     + bf2f((u16)(w1[i] >> 16));
    }
  }
#pragma unroll
  for (int i = 0; i < 8; ++i) {
    s[i] += __shfl_xor(s[i], 16, 64);
    s[i] += __shfl_xor(s[i], 32, 64);
  }
  if (g == 0) {
    uint4 o;
    o.x = (u32)f2bf(s[0]) | ((u32)f2bf(s[1]) << 16);
    o.y = (u32)f2bf(s[2]) | ((u32)f2bf(s[3]) << 16);
    o.z = (u32)f2bf(s[4]) | ((u32)f2bf(s[5]) << 16);
    o.w = (u32)f2bf(s[6]) | ((u32)f2bf(s[7]) << 16);
    *(uint4*)(agg + (size_t)node * 128 + l * 8) = o;
  }
}

// ---------------- parallel segmented mean-pool (batch is sorted) ----------------
__global__ __launch_bounds__(256)
void pool_kernel(const u16* __restrict__ h, const int* __restrict__ batch,
                 const int* __restrict__ flags, float* __restrict__ sums)
{
  const int c = threadIdx.x & 127;
  const int half = threadIdx.x >> 7;
  const int base = blockIdx.x * 128;
  const int f = flags[1];
  int gcur = -1; float s = 0.f;
  for (int i = half; i < 128; i += 2) {
    int n = base + i;
    if (n >= N_NODES) break;
    int g = geti(batch, n, f);
    if (g != gcur) {
      if (gcur >= 0) atomicAdd(&sums[gcur * 128 + c], s);
      s = 0.f; gcur = g;
    }
    s += bf2f(h[(size_t)n * 128 + c]);
  }
  if (gcur >= 0) atomicAdd(&sums[gcur * 128 + c], s);
}

// ---------------- doc proj + LN + fusion + heads, f32 (one block per graph) ----------------
__global__ __launch_bounds__(256)
void head2_kernel(const float* __restrict__ sums, const int* __restrict__ batch,
                  const int* __restrict__ flags,
                  const float* __restrict__ doc, const float* __restrict__ doc_w, const float* __restrict__ doc_b,
                  const float* __restrict__ ln_g, const float* __restrict__ ln_b,
                  const float* __restrict__ fus_w, const float* __restrict__ fus_b,
                  const float* __restrict__ task_w, const float* __restrict__ task_b,
                  const float* __restrict__ time_w, const float* __restrict__ time_b,
                  float* __restrict__ out_task, float* __restrict__ out_time)
{
  const int g = blockIdx.x;
  const int t = threadIdx.x;
  __shared__ float fusion[256];
  __shared__ float fh[128];
  __shared__ float dpart[256];
  __shared__ int seg[2];

  if (t < 2) {
    int f = flags[1];
    int target = g + t, lo = 0, hi = N_NODES;
    while (lo < hi) { int mid = (lo + hi) >> 1; if (geti(batch, mid, f) < target) lo = mid + 1; else hi = mid; }
    seg[t] = lo;
  }
  {
    int c = t & 127, kh = t >> 7;
    float s = 0.f;
    for (int k = kh * 384; k < kh * 384 + 384; ++k) s += doc[g * 768 + k] * doc_w[k * 128 + c];
    dpart[t] = s;
  }
  __syncthreads();

  if (t < 128) {
    float cnt = (float)(seg[1] - seg[0]);
    fusion[t] = sums[g * 128 + t] / fmaxf(cnt, 1.f);
  } else {
    int c = t - 128;
    fusion[t] = fmaxf(dpart[c] + dpart[c + 128] + doc_b[c], 0.f);
  }
  __syncthreads();

  float mu = 0.f;
  for (int i = 0; i < 256; ++i) mu += fusion[i];
  mu *= (1.f / 256.f);
  float var = 0.f;
  for (int i = 0; i < 256; ++i) { float d = fusion[i] - mu; var += d * d; }
  var *= (1.f / 256.f);
  float inv = rsqrtf(var + 1e-5f);
  float norm = (fusion[t] - mu) * inv * ln_g[t] + ln_b[t];
  __syncthreads();
  fusion[t] = norm;
  __syncthreads();

  if (t < 128) {
    float s = 0.f;
    for (int k = 0; k < 256; ++k) s += fusion[k] * fus_w[k * 128 + t];
    s += fus_b[t];
    fh[t] = fmaxf(s, 0.f);
  }
  __syncthreads();

  if (t < 32) {
    float s = 0.f;
    for (int k = 0; k < 128; ++k) s += fh[k] * task_w[k * 32 + t];
    s += task_b[t];
    out_task[g * 32 + t] = s;
  }
  if (t == 32) {
    float s = 0.f;
    for (int k = 0; k < 128; ++k) s += fh[k] * time_w[k];
    s += time_b[0];
    out_time[g] = s;
  }
}

// ---------------- launch ----------------
extern "C" void kernel_launch(void* const* d_in, const int* in_sizes, int n_in,
                              void* d_out, int out_size, void* d_ws, size_t ws_size,
                              hipStream_t stream)
{
  const float* x        = (const float*)d_in[0];
  const float* doc      = (const float*)d_in[1];
  const int*   ei       = (const int*)d_in[2];
  const int*   batch    = (const int*)d_in[3];
  const float* node_w   = (const float*)d_in[4];
  const float* node_b   = (const float*)d_in[5];
  const float* ggnn_w   = (const float*)d_in[6];
  const float* gru_w_ih = (const float*)d_in[7];
  const float* gru_b_ih = (const float*)d_in[8];
  const float* gru_w_hh = (const float*)d_in[9];
  const float* gru_b_hh = (const float*)d_in[10];
  const float* doc_w    = (const float*)d_in[11];
  const float* doc_b    = (const float*)d_in[12];
  const float* ln_g     = (const float*)d_in[13];
  const float* ln_b     = (const float*)d_in[14];
  const float* fus_w    = (const float*)d_in[15];
  const float* fus_b    = (const float*)d_in[16];
  const float* task_w   = (const float*)d_in[17];
  const float* task_b   = (const float*)d_in[18];
  const float* time_w   = (const float*)d_in[19];
  const float* time_b   = (const float*)d_in[20];

  char* ws = (char*)d_ws;
  size_t off = 0;
  auto alloc = [&](size_t bytes) -> void* {
    void* p = ws + off;
    off = (off + bytes + 255) & ~(size_t)255;
    return p;
  };
  u16* aggb    = (u16*)alloc((size_t)N_NODES * 128 * 2);   // 25.6 MB
  u16* hA      = (u16*)alloc((size_t)N_NODES * 128 * 2);
  u16* hB      = (u16*)alloc((size_t)N_NODES * 128 * 2);
  u16* nwT     = (u16*)alloc(64 * 128 * 2);
  u16* b2q     = (u16*)alloc(3 * 98304 * 2);
  float* wp    = (float*)alloc(3 * 128 * 384 * 4);
  float* sums  = (float*)alloc(N_GRAPHS * 128 * 4);
  int* counts  = (int*)alloc((size_t)N_NODES * 4);
  int* offs    = (int*)alloc((size_t)(N_NODES + 1) * 4);
  int* ssrc    = (int*)alloc((size_t)N_EDGES * 4);
  int* bsum    = (int*)alloc(SCAN_BLK_BKT * 4);
  int* bbase   = (int*)alloc(SCAN_BLK_BKT * 4);
  int* flags   = (int*)alloc(2 * 4);

  // CSR-build scratch ALIASED into aggb (dead before agg_kernel writes aggb).
  u32* bedges  = (u32*)aggb;                                        // 6,400,000 B
  int* bcounts = (int*)((char*)aggb + 6400000);                     // 800,768 B (256-aligned)
  int* bbases  = (int*)((char*)aggb + 7200768);                     // 800,772 B (256-aligned)

  hipMemsetAsync(sums, 0, (size_t)N_GRAPHS * 128 * 4, stream);

  detect_i64_kernel<<<1, 64, 0, stream>>>(ei, batch, flags);

  // CSR build: counting sort, zero global atomics.
  bucket_hist<<<NBLK_P1, 256, 0, stream>>>(ei, flags, bcounts);
  scanA_kernel<<<SCAN_BLK_BKT, 1024, 0, stream>>>(bcounts, BKT_SCAN_N, bsum);
  scanB_kernel<<<1, 64, 0, stream>>>(bsum, SCAN_BLK_BKT, bbase, (int*)nullptr);
  scanC_kernel<<<SCAN_BLK_BKT, 1024, 0, stream>>>(bcounts, BKT_SCAN_N, bbase, bbases);
  bucket_scatter<<<NBLK_P1, 256, 0, stream>>>(ei, flags, bbases, bedges);
  node_count<<<NBUCK, 256, 0, stream>>>(bedges, bbases, counts);
  scanA_kernel<<<SCAN_BLK_NODE, 1024, 0, stream>>>(counts, N_NODES, bsum);
  scanB_kernel<<<1, 64, 0, stream>>>(bsum, SCAN_BLK_NODE, bbase, offs + N_NODES);
  scanC_kernel<<<SCAN_BLK_NODE, 1024, 0, stream>>>(counts, N_NODES, bbase, offs);
  final_scatter<<<NBUCK, 256, 0, stream>>>(bedges, bbases, offs, ssrc);

  transpose_kernel<<<(64 * 128 + 255) / 256, 256, 0, stream>>>(node_w, nwT, 64, 128);
  wprime_kernel<<<(3 * 128 * 384 + 255) / 256, 256, 0, stream>>>(ggnn_w, gru_w_ih, wp);
  for (int l = 0; l < 3; ++l)
    build_b2q_kernel<<<(98304 + 255) / 256, 256, 0, stream>>>(
        wp + l * 128 * 384, gru_w_hh, b2q + (size_t)l * 98304);

  const int GB = (N_NODES + 63) / 64;            // 1563
  const int GBGRU = ((N_NODES + 63) / 64) * 4;   // 1563 strips x 4 octant-pairs = 6252
  nodeproj_gemm<<<GB, 256, 0, stream>>>(x, nwT, node_b, hA, N_NODES);

  u16* hcur = hA;
  u16* hnext = hB;
  for (int l = 0; l < 3; ++l) {
    agg_kernel<<<(N_NODES + 3) / 4, 256, 0, stream>>>(hcur, ssrc, offs, aggb);
    gru_gemm<<<GBGRU, 256, 0, stream>>>(aggb, hcur, b2q + (size_t)l * 98304,
                                        gru_b_ih, gru_b_hh, hnext, N_NODES);
    u16* tmp = hcur; hcur = hnext; hnext = tmp;
  }

  pool_kernel<<<(N_NODES + 127) / 128, 256, 0, stream>>>(hcur, batch, flags, sums);

  float* out_task = (float*)d_out;
  float* out_time = out_task + N_GRAPHS * 32;
  head2_kernel<<<N_GRAPHS, 256, 0, stream>>>(sums, batch, flags, doc, doc_w, doc_b, ln_g, ln_b,
                                             fus_w, fus_b, task_w, task_b, time_w, time_b,
                                             out_task, out_time);
}